// Round 4
// baseline (585.128 us; speedup 1.0000x reference)
//
#include <hip/hip_runtime.h>
#include <cstdint>

// HiPPO-LegS scan x_t = A_t x_{t-1} + B_t * u_t  via chunked parallel scan.
// L=4096, B=256, N=64.  Subchunks of 16 (256), superchunks of 64 (64).
// K1 (fused): suffix products + w_t per subchunk AND fp16 hi/lo slot production
// K1b: combine 4 subchunks -> superchunk product P_s, upgrade w_t (64 blocks)
// K1c: z_s[b] = sum_t inputs[t,b] * w_t  (small GEMM, 256 blocks)
// K2: sequential carry, double-buffered Pt/xb -> ONE barrier per step (64 blocks)
// K3 (MFMA): scan inside each superchunk; triple-buffered A-slot prefetch with
//            counted s_waitcnt vmcnt(N) (never 0 in main loop) + double-buffered
//            X -> ONE barrier per step.  batch tile 32, grid 512, 2 blocks/CU.

#define TID ((int)threadIdx.x)

typedef _Float16 half8 __attribute__((ext_vector_type(8)));
typedef _Float16 half4v __attribute__((ext_vector_type(4)));
typedef float f32x4 __attribute__((ext_vector_type(4)));

constexpr int SUBL  = 16;
constexpr int PAD   = 68;   // fp32 LDS row pad

// ws layout (floats)
constexpr size_t WS_W = 0;                       // 4096*64
constexpr size_t WS_Q = 262144;                  // 256*4096
constexpr size_t WS_P = WS_Q + 1048576;          // 64*4096
constexpr size_t WS_Z = WS_P + 262144;           // 64*256*64
constexpr size_t WS_H = WS_Z + 1048576;          // 64*256*64
constexpr size_t OLD_WS_FLOATS = WS_H + 1048576;

// A-slot layout for MFMA path (bytes per step t)
constexpr int SLOT   = 20480;   // 20 KB: 5 x (256 lanes x 16 B) staging chunks
constexpr int APITCH = 144;     // 72 fp16 per row (4-bank shift -> <=2-way conflicts)
constexpr int AL_OFF = 9216;    // Al array
constexpr int BV_OFF = 18432;   // Bv f32[64]
constexpr int U_OFF  = 18688;   // inputs row f32[256]
constexpr size_t AWS_BYTES = (size_t)4096 * SLOT;

// ---------------- shared helpers (fp32 path) ----------------
__device__ __forceinline__ void stage64x64(const float* __restrict__ g, float* __restrict__ l) {
#pragma unroll
  for (int r = 0; r < 4; ++r) {
    int id = TID + 256 * r;
    int i = id >> 4, j0 = (id & 15) << 2;
    *reinterpret_cast<float4*>(&l[i * PAD + j0]) =
        *reinterpret_cast<const float4*>(&g[i * 64 + j0]);
  }
}

__device__ __forceinline__ void matmul_tile(const float* __restrict__ Ml,
                                            const float* __restrict__ Al,
                                            float* __restrict__ Dl,
                                            int i_lo, int i_hi) {
  float acc[4][4];
#pragma unroll
  for (int a = 0; a < 4; ++a)
#pragma unroll
    for (int b = 0; b < 4; ++b) acc[a][b] = 0.f;
  const int j0 = i_hi << 2;
#pragma unroll
  for (int kq = 0; kq < 16; ++kq) {
    const int k0 = kq << 2;
    float4 mf[4], af[4];
#pragma unroll
    for (int a = 0; a < 4; ++a)
      mf[a] = *reinterpret_cast<const float4*>(&Ml[(i_lo + 16 * a) * PAD + k0]);
#pragma unroll
    for (int kk = 0; kk < 4; ++kk)
      af[kk] = *reinterpret_cast<const float4*>(&Al[(k0 + kk) * PAD + j0]);
#pragma unroll
    for (int a = 0; a < 4; ++a) {
      acc[a][0] += mf[a].x * af[0].x + mf[a].y * af[1].x + mf[a].z * af[2].x + mf[a].w * af[3].x;
      acc[a][1] += mf[a].x * af[0].y + mf[a].y * af[1].y + mf[a].z * af[2].y + mf[a].w * af[3].y;
      acc[a][2] += mf[a].x * af[0].z + mf[a].y * af[1].z + mf[a].z * af[2].z + mf[a].w * af[3].z;
      acc[a][3] += mf[a].x * af[0].w + mf[a].y * af[1].w + mf[a].z * af[2].w + mf[a].w * af[3].w;
    }
  }
#pragma unroll
  for (int a = 0; a < 4; ++a)
    *reinterpret_cast<float4*>(&Dl[(i_lo + 16 * a) * PAD + j0]) =
        make_float4(acc[a][0], acc[a][1], acc[a][2], acc[a][3]);
}

// ---------------- K1 fused: suffix products + w_t + fp16 hi/lo slots ----------------
__global__ __launch_bounds__(256) void k1_fused(const float* __restrict__ Ag,
                                                const float* __restrict__ Bg,
                                                const float* __restrict__ inp,
                                                unsigned char* __restrict__ Aws,
                                                float* __restrict__ W,
                                                float* __restrict__ Qw) {
  __shared__ float Ms[2][64 * PAD];
  __shared__ float As[2][64 * PAD];
  __shared__ float Bvs[2][64];
  const int c = blockIdx.x;
  const int i_lo = TID & 15, i_hi = TID >> 4;
  const int r_i0 = TID >> 4;          // staged rows: r_i0 + 16*r
  const int r_j0 = (TID & 15) << 2;   // staged cols: r_j0 .. r_j0+3

  for (int idx = TID; idx < 64 * PAD; idx += 256) Ms[0][idx] = 0.f;

  // prologue: A(t=15), Bv(t=15) -> regs
  float4 pc[4];
  float4 bvc = make_float4(0.f, 0.f, 0.f, 0.f);
  {
    const float* g = Ag + (size_t)(c * SUBL + SUBL - 1) * 4096;
#pragma unroll
    for (int r = 0; r < 4; ++r)
      pc[r] = *reinterpret_cast<const float4*>(&g[(r_i0 + 16 * r) * 64 + r_j0]);
    if (TID < 16)
      bvc = *reinterpret_cast<const float4*>(&Bg[(size_t)(c * SUBL + SUBL - 1) * 64 + TID * 4]);
  }
  __syncthreads();
  if (TID < 64) Ms[0][TID * PAD + TID] = 1.f;
#pragma unroll
  for (int r = 0; r < 4; ++r)
    *reinterpret_cast<float4*>(&As[0][(r_i0 + 16 * r) * PAD + r_j0]) = pc[r];
  if (TID < 16) *reinterpret_cast<float4*>(&Bvs[0][TID * 4]) = bvc;
  __syncthreads();

  int cur = 0, ab = 0;
  for (int k = SUBL - 1; k >= 0; --k) {
    const int t = c * SUBL + k;
    unsigned char* slot = Aws + (size_t)t * SLOT;
    // prefetch next step's A, Bv into regs (latency hidden under this step)
    float4 pn[4];
    float4 bvn = make_float4(0.f, 0.f, 0.f, 0.f);
    if (k > 0) {
      const float* g = Ag + (size_t)(t - 1) * 4096;
#pragma unroll
      for (int r = 0; r < 4; ++r)
        pn[r] = *reinterpret_cast<const float4*>(&g[(r_i0 + 16 * r) * 64 + r_j0]);
      if (TID < 16)
        bvn = *reinterpret_cast<const float4*>(&Bg[(size_t)(t - 1) * 64 + TID * 4]);
    }
    // u-row copy to slot
    if (TID >= 64 && TID < 128) {
      int q = TID - 64;
      *reinterpret_cast<float4*>(slot + U_OFF + q * 16) =
          *reinterpret_cast<const float4*>(inp + (size_t)t * 256 + q * 4);
    }
    // Bv slot write (regs held from previous iteration)
    if (TID < 16) *reinterpret_cast<float4*>(slot + BV_OFF + TID * 16) = bvc;
    // w_t = M_suffix @ Bv
    if (TID < 64) {
      float wv = 0.f;
#pragma unroll
      for (int kq = 0; kq < 16; ++kq) {
        float4 m = *reinterpret_cast<const float4*>(&Ms[cur][TID * PAD + kq * 4]);
        float4 b = *reinterpret_cast<const float4*>(&Bvs[ab][kq * 4]);
        wv += m.x * b.x + m.y * b.y + m.z * b.z + m.w * b.w;
      }
      W[t * 64 + TID] = wv;
    }
    // fp16 hi/lo split from registers -> global slot (K0 fused here)
#pragma unroll
    for (int r = 0; r < 4; ++r) {
      float vv[4] = {pc[r].x, pc[r].y, pc[r].z, pc[r].w};
      half4v hh, ll;
#pragma unroll
      for (int e = 0; e < 4; ++e) {
        _Float16 h = (_Float16)vv[e];
        hh[e] = h;
        ll[e] = (_Float16)(vv[e] - (float)h);
      }
      const int row = r_i0 + 16 * r;
      *reinterpret_cast<half4v*>(slot + row * APITCH + r_j0 * 2) = hh;
      *reinterpret_cast<half4v*>(slot + AL_OFF + row * APITCH + r_j0 * 2) = ll;
    }
    if (TID < 64) {  // zero row pad (cols 64..71)
      half8 z = {};
      *reinterpret_cast<half8*>(slot + TID * APITCH + 128) = z;
      *reinterpret_cast<half8*>(slot + AL_OFF + TID * APITCH + 128) = z;
    }
    // suffix product
    matmul_tile(Ms[cur], As[ab], Ms[cur ^ 1], i_lo, i_hi);
    // late write of prefetched data into the other LDS buffers
    if (k > 0) {
#pragma unroll
      for (int r = 0; r < 4; ++r)
        *reinterpret_cast<float4*>(&As[ab ^ 1][(r_i0 + 16 * r) * PAD + r_j0]) = pn[r];
      if (TID < 16) *reinterpret_cast<float4*>(&Bvs[ab ^ 1][TID * 4]) = bvn;
#pragma unroll
      for (int r = 0; r < 4; ++r) pc[r] = pn[r];
      bvc = bvn;
    }
    __syncthreads();
    cur ^= 1;
    ab ^= 1;
  }
#pragma unroll
  for (int r = 0; r < 4; ++r) {
    int id = TID + 256 * r;
    int i = id >> 4, j0 = (id & 15) << 2;
    *reinterpret_cast<float4*>(&Qw[(size_t)c * 4096 + i * 64 + j0]) =
        *reinterpret_cast<const float4*>(&Ms[cur][i * PAD + j0]);
  }
}

// ---------------- K1 (fp32 fallback, no slot production) ----------------
__global__ __launch_bounds__(256) void k1_suffix(const float* __restrict__ Ag,
                                                 const float* __restrict__ Bg,
                                                 float* __restrict__ W,
                                                 float* __restrict__ Qw) {
  __shared__ float Ms[2][64 * PAD];
  __shared__ float As[64 * PAD];
  __shared__ float Bvs[64];
  const int c = blockIdx.x;
  const int i_lo = TID & 15, i_hi = TID >> 4;
  for (int idx = TID; idx < 64 * PAD; idx += 256) Ms[0][idx] = 0.f;
  __syncthreads();
  if (TID < 64) Ms[0][TID * PAD + TID] = 1.f;
  int cur = 0;
  for (int k = SUBL - 1; k >= 0; --k) {
    const int t = c * SUBL + k;
    stage64x64(Ag + (size_t)t * 4096, As);
    if (TID < 16)
      *reinterpret_cast<float4*>(&Bvs[TID * 4]) =
          *reinterpret_cast<const float4*>(&Bg[t * 64 + TID * 4]);
    __syncthreads();
    if (TID < 64) {
      float wv = 0.f;
#pragma unroll
      for (int kq = 0; kq < 16; ++kq) {
        float4 m = *reinterpret_cast<const float4*>(&Ms[cur][TID * PAD + kq * 4]);
        float4 b = *reinterpret_cast<const float4*>(&Bvs[kq * 4]);
        wv += m.x * b.x + m.y * b.y + m.z * b.z + m.w * b.w;
      }
      W[t * 64 + TID] = wv;
    }
    matmul_tile(Ms[cur], As, Ms[cur ^ 1], i_lo, i_hi);
    __syncthreads();
    cur ^= 1;
  }
#pragma unroll
  for (int r = 0; r < 4; ++r) {
    int id = TID + 256 * r;
    int i = id >> 4, j0 = (id & 15) << 2;
    *reinterpret_cast<float4*>(&Qw[(size_t)c * 4096 + i * 64 + j0]) =
        *reinterpret_cast<const float4*>(&Ms[cur][i * PAD + j0]);
  }
}

// ---------------- K1b: combine subchunks -> superchunk; upgrade w ----------------
__global__ __launch_bounds__(256) void k1b_combine(const float* __restrict__ Qw,
                                                   float* __restrict__ W,
                                                   float* __restrict__ Pw) {
  __shared__ float R[2][64 * PAD];
  __shared__ float Qs[64 * PAD];
  __shared__ float wm[16 * PAD];
  const int s = blockIdx.x;
  const int i_lo = TID & 15, i_hi = TID >> 4;
  int cur = 0;
  for (int m = 3; m >= 0; --m) {
    const int c = 4 * s + m;
    stage64x64(Qw + (size_t)c * 4096, Qs);
    {
      int tt = TID >> 4, i0 = (TID & 15) << 2;
      *reinterpret_cast<float4*>(&wm[tt * PAD + i0]) =
          *reinterpret_cast<const float4*>(&W[(size_t)(c * 16 + tt) * 64 + i0]);
    }
    __syncthreads();
    if (m < 3) {
      float acc[4] = {0.f, 0.f, 0.f, 0.f};
#pragma unroll
      for (int kq = 0; kq < 16; ++kq) {
        const int k0 = kq << 2;
        float4 wf = *reinterpret_cast<const float4*>(&wm[i_hi * PAD + k0]);
#pragma unroll
        for (int a = 0; a < 4; ++a) {
          float4 rf = *reinterpret_cast<const float4*>(&R[cur][(i_lo + 16 * a) * PAD + k0]);
          acc[a] += rf.x * wf.x + rf.y * wf.y + rf.z * wf.z + rf.w * wf.w;
        }
      }
#pragma unroll
      for (int a = 0; a < 4; ++a)
        W[(size_t)(c * 16 + i_hi) * 64 + i_lo + 16 * a] = acc[a];
      matmul_tile(R[cur], Qs, R[cur ^ 1], i_lo, i_hi);
    } else {
#pragma unroll
      for (int r = 0; r < 4; ++r) {
        int id = TID + 256 * r;
        int i = id >> 4, j0 = (id & 15) << 2;
        *reinterpret_cast<float4*>(&R[cur ^ 1][i * PAD + j0]) =
            *reinterpret_cast<const float4*>(&Qs[i * PAD + j0]);
      }
    }
    __syncthreads();
    cur ^= 1;
  }
#pragma unroll
  for (int r = 0; r < 4; ++r) {
    int id = TID + 256 * r;
    int i = id >> 4, j0 = (id & 15) << 2;
    *reinterpret_cast<float4*>(&Pw[(size_t)s * 4096 + i * 64 + j0]) =
        *reinterpret_cast<const float4*>(&R[cur][i * PAD + j0]);
  }
}

// ---------------- K1c: z_s[b,i] = sum_t inputs[t,b]*w_t[i] ----------------
__global__ __launch_bounds__(256) void k1c_zgemm(const float* __restrict__ inp,
                                                 const float* __restrict__ W,
                                                 float* __restrict__ Zw) {
  __shared__ float inT[64 * PAD];
  __shared__ float wm[64 * PAD];
  const int s = blockIdx.x >> 2, g = blockIdx.x & 3;
  const int b0 = 64 * g, t0 = s * 64;
  const int i_lo = TID & 15, i_hi = TID >> 4;
#pragma unroll
  for (int r = 0; r < 4; ++r) {
    int id = TID + 256 * r;
    int tl = id >> 4, b4 = (id & 15) << 2;
    float4 v = *reinterpret_cast<const float4*>(&inp[(size_t)(t0 + tl) * 256 + b0 + b4]);
    inT[(b4 + 0) * PAD + tl] = v.x;
    inT[(b4 + 1) * PAD + tl] = v.y;
    inT[(b4 + 2) * PAD + tl] = v.z;
    inT[(b4 + 3) * PAD + tl] = v.w;
  }
#pragma unroll
  for (int r = 0; r < 4; ++r) {
    int id = TID + 256 * r;
    int tl = id >> 4, i0 = (id & 15) << 2;
    *reinterpret_cast<float4*>(&wm[tl * PAD + i0]) =
        *reinterpret_cast<const float4*>(&W[(size_t)(t0 + tl) * 64 + i0]);
  }
  __syncthreads();
  float acc[4][4];
#pragma unroll
  for (int a = 0; a < 4; ++a)
#pragma unroll
    for (int q = 0; q < 4; ++q) acc[a][q] = 0.f;
  const int j0c = i_hi << 2;
#pragma unroll
  for (int kq = 0; kq < 16; ++kq) {
    const int k0 = kq << 2;
    float4 bf[4], wf[4];
#pragma unroll
    for (int a = 0; a < 4; ++a)
      bf[a] = *reinterpret_cast<const float4*>(&inT[(i_lo + 16 * a) * PAD + k0]);
#pragma unroll
    for (int kk = 0; kk < 4; ++kk)
      wf[kk] = *reinterpret_cast<const float4*>(&wm[(k0 + kk) * PAD + j0c]);
#pragma unroll
    for (int a = 0; a < 4; ++a) {
      acc[a][0] += bf[a].x * wf[0].x + bf[a].y * wf[1].x + bf[a].z * wf[2].x + bf[a].w * wf[3].x;
      acc[a][1] += bf[a].x * wf[0].y + bf[a].y * wf[1].y + bf[a].z * wf[2].y + bf[a].w * wf[3].y;
      acc[a][2] += bf[a].x * wf[0].z + bf[a].y * wf[1].z + bf[a].z * wf[2].z + bf[a].w * wf[3].z;
      acc[a][3] += bf[a].x * wf[0].w + bf[a].y * wf[1].w + bf[a].z * wf[2].w + bf[a].w * wf[3].w;
    }
  }
  __syncthreads();
#pragma unroll
  for (int a = 0; a < 4; ++a)
    *reinterpret_cast<float4*>(&wm[(i_lo + 16 * a) * PAD + j0c]) =
        make_float4(acc[a][0], acc[a][1], acc[a][2], acc[a][3]);
  __syncthreads();
#pragma unroll
  for (int r = 0; r < 4; ++r) {
    int id = TID + 256 * r;
    int bl = id >> 4, i0 = (id & 15) << 2;
    *reinterpret_cast<float4*>(&Zw[(size_t)s * 16384 + (b0 + bl) * 64 + i0]) =
        *reinterpret_cast<const float4*>(&wm[bl * PAD + i0]);
  }
}

// ---------------- K2: sequential carry, double-buffered -> one barrier/step ----------------
__global__ __launch_bounds__(256) void k2_carry(const float* __restrict__ Pw,
                                                const float* __restrict__ Zw,
                                                float* __restrict__ Hw) {
  __shared__ float Pt[2][64 * PAD];
  __shared__ float xb[2][4 * PAD];
  const int g = blockIdx.x;
  const int bl = TID >> 6, i = TID & 63;
  const int bg = 4 * g + bl;
  const int ir = TID >> 4, j0 = (TID & 15) << 2;
  for (int idx = TID; idx < 4 * PAD; idx += 256) xb[0][idx] = 0.f;
  // prologue: stage P(0) transposed + z(0)
  float4 p0[4];
#pragma unroll
  for (int r = 0; r < 4; ++r)
    p0[r] = *reinterpret_cast<const float4*>(&Pw[(ir + 16 * r) * 64 + j0]);
  float zc = Zw[(size_t)bg * 64 + i];
#pragma unroll
  for (int r = 0; r < 4; ++r) {
    int row = ir + 16 * r;
    Pt[0][(j0 + 0) * PAD + row] = p0[r].x;
    Pt[0][(j0 + 1) * PAD + row] = p0[r].y;
    Pt[0][(j0 + 2) * PAD + row] = p0[r].z;
    Pt[0][(j0 + 3) * PAD + row] = p0[r].w;
  }
  __syncthreads();
  float h = 0.f;
  for (int s = 0; s < 64; ++s) {
    const int rb = s & 1, wb = rb ^ 1;
    // issue next-step loads early; latency hides under this step's compute
    float4 pn[4];
    float zn = 0.f;
    if (s < 63) {
#pragma unroll
      for (int r = 0; r < 4; ++r)
        pn[r] = *reinterpret_cast<const float4*>(
            &Pw[(size_t)(s + 1) * 4096 + (ir + 16 * r) * 64 + j0]);
      zn = Zw[(size_t)(s + 1) * 16384 + bg * 64 + i];
    }
    Hw[(size_t)s * 16384 + bg * 64 + i] = h;
    float acc = zc;
#pragma unroll
    for (int jq = 0; jq < 16; ++jq) {
      const int jj = jq << 2;
      float4 xf = *reinterpret_cast<const float4*>(&xb[rb][bl * PAD + jj]);
      acc += Pt[rb][(jj + 0) * PAD + i] * xf.x + Pt[rb][(jj + 1) * PAD + i] * xf.y +
             Pt[rb][(jj + 2) * PAD + i] * xf.z + Pt[rb][(jj + 3) * PAD + i] * xf.w;
    }
    h = acc;
    // write next-step state into the OTHER buffers (no WAR: their readers
    // finished before the previous barrier)
    xb[wb][bl * PAD + i] = h;
    if (s < 63) {
#pragma unroll
      for (int r = 0; r < 4; ++r) {
        int row = ir + 16 * r;
        Pt[wb][(j0 + 0) * PAD + row] = pn[r].x;
        Pt[wb][(j0 + 1) * PAD + row] = pn[r].y;
        Pt[wb][(j0 + 2) * PAD + row] = pn[r].z;
        Pt[wb][(j0 + 3) * PAD + row] = pn[r].w;
      }
      zc = zn;
    }
    __syncthreads();  // single barrier: new Pt/xb visible for step s+1
  }
}

// ---------------- K3 (fp32 fallback) ----------------
__global__ __launch_bounds__(256) void k3_final(const float* __restrict__ Ag,
                                                const float* __restrict__ Bg,
                                                const float* __restrict__ inp,
                                                const float* __restrict__ Hw,
                                                float* __restrict__ out) {
  __shared__ float As[64 * PAD];
  __shared__ float xs[64 * PAD];
  __shared__ float Bvs[64];
  __shared__ float ins[64];
  const int s = blockIdx.x >> 2, g = blockIdx.x & 3;
  const int b0 = 64 * g;
  const int i_lo = TID & 15, i_hi = TID >> 4;
#pragma unroll
  for (int r = 0; r < 4; ++r) {
    int id = TID + 256 * r;
    int bl = id >> 4, i0 = (id & 15) << 2;
    *reinterpret_cast<float4*>(&xs[bl * PAD + i0]) =
        *reinterpret_cast<const float4*>(&Hw[(size_t)s * 16384 + (b0 + bl) * 64 + i0]);
  }
  for (int k = 0; k < 64; ++k) {
    const int t = s * 64 + k;
    stage64x64(Ag + (size_t)t * 4096, As);
    if (TID < 16)
      *reinterpret_cast<float4*>(&Bvs[TID * 4]) =
          *reinterpret_cast<const float4*>(&Bg[t * 64 + TID * 4]);
    if (TID >= 64 && TID < 80) {
      int q = TID - 64;
      *reinterpret_cast<float4*>(&ins[q * 4]) =
          *reinterpret_cast<const float4*>(&inp[(size_t)t * 256 + b0 + q * 4]);
    }
    __syncthreads();
    float acc[4][4];
#pragma unroll
    for (int a = 0; a < 4; ++a)
#pragma unroll
      for (int r = 0; r < 4; ++r) acc[a][r] = 0.f;
#pragma unroll
    for (int jq = 0; jq < 16; ++jq) {
      const int j0 = jq << 2;
      float4 af[4], xf[4];
#pragma unroll
      for (int a = 0; a < 4; ++a)
        af[a] = *reinterpret_cast<const float4*>(&As[(i_lo + 16 * a) * PAD + j0]);
#pragma unroll
      for (int r = 0; r < 4; ++r)
        xf[r] = *reinterpret_cast<const float4*>(&xs[(i_hi + 16 * r) * PAD + j0]);
#pragma unroll
      for (int a = 0; a < 4; ++a)
#pragma unroll
        for (int r = 0; r < 4; ++r)
          acc[a][r] += af[a].x * xf[r].x + af[a].y * xf[r].y + af[a].z * xf[r].z + af[a].w * xf[r].w;
    }
    float bv[4], ui[4];
#pragma unroll
    for (int a = 0; a < 4; ++a) bv[a] = Bvs[i_lo + 16 * a];
#pragma unroll
    for (int r = 0; r < 4; ++r) ui[r] = ins[i_hi + 16 * r];
#pragma unroll
    for (int a = 0; a < 4; ++a)
#pragma unroll
      for (int r = 0; r < 4; ++r) acc[a][r] += bv[a] * ui[r];
    __syncthreads();
#pragma unroll
    for (int r = 0; r < 4; ++r)
#pragma unroll
      for (int a = 0; a < 4; ++a)
        xs[(i_hi + 16 * r) * PAD + i_lo + 16 * a] = acc[a][r];
    __syncthreads();
#pragma unroll
    for (int r = 0; r < 4; ++r) {
      int id = TID + 256 * r;
      int bl = id >> 4, i0 = (id & 15) << 2;
      *reinterpret_cast<float4*>(&out[((size_t)t * 256 + b0 + bl) * 64 + i0]) =
          *reinterpret_cast<const float4*>(&xs[bl * PAD + i0]);
    }
  }
}

// ---------------- K3 (MFMA fp16 hi/lo, counted-vmcnt pipeline) ----------------
__device__ __forceinline__ void gload_lds16(const void* g, void* l) {
  __builtin_amdgcn_global_load_lds(
      (const __attribute__((address_space(1))) unsigned int*)g,
      (__attribute__((address_space(3))) unsigned int*)l, 16, 0, 0);
}

constexpr int XROWS  = 32;
constexpr int XHALF  = XROWS * APITCH;       // 4608 (one of hi/lo)
constexpr int XBUF   = 2 * XHALF;            // 9216 (hi+lo)
constexpr int LDS_X0 = 3 * SLOT;             // 61440 (3 A-slot buffers)
constexpr int LDS_SZ = LDS_X0 + 2 * XBUF;    // 79872 -> 2 blocks/CU (159744 <= 160K)

__global__ __launch_bounds__(256, 2) void k3_mfma(const unsigned char* __restrict__ Aws,
                                                  const float* __restrict__ Hw,
                                                  float* __restrict__ out) {
  __shared__ __align__(16) unsigned char sm[LDS_SZ];
  const int blk = blockIdx.x;
  // XCD swizzle: the 8 batch-group blocks of one superchunk land 8 apart -> same XCD L2
  const int s = (blk & 7) | ((blk >> 6) << 3);
  const int g = (blk >> 3) & 7;
  const int b0 = g << 5;
  const int lane = TID & 63, wave = TID >> 6;
  const int lm = lane & 15, quad = lane >> 4;
  const int wm = wave >> 1, wn = wave & 1;  // 2x2 wave grid: wm over i(32), wn over b(16)

  // init X buf0 (fp16 hi/lo, [b][j] pitch 144 B) from Hw fp32 (32 batch rows)
#pragma unroll
  for (int r = 0; r < 2; ++r) {
    int id = TID + (r << 8);
    int bl = id >> 4, j0 = (id & 15) << 2;
    float4 v = *reinterpret_cast<const float4*>(
        &Hw[(size_t)s * 16384 + (size_t)(b0 + bl) * 64 + j0]);
    float vv[4] = {v.x, v.y, v.z, v.w};
    half4v hh, ll;
#pragma unroll
    for (int e = 0; e < 4; ++e) {
      _Float16 h = (_Float16)vv[e];
      hh[e] = h;
      ll[e] = (_Float16)(vv[e] - (float)h);
    }
    *reinterpret_cast<half4v*>(sm + LDS_X0 + bl * APITCH + (j0 << 1)) = hh;
    *reinterpret_cast<half4v*>(sm + LDS_X0 + XHALF + bl * APITCH + (j0 << 1)) = ll;
  }

  const size_t t0 = (size_t)s * 64;
  // prefetch slots 0 and 1 -> buffers 0 and 1 (10 vmem ops/wave)
#pragma unroll
  for (int sl = 0; sl < 2; ++sl) {
    const unsigned char* gsl = Aws + (t0 + sl) * SLOT;
#pragma unroll
    for (int r = 0; r < 5; ++r) {
      int off = ((r << 2) + wave) << 10;
      gload_lds16(gsl + off + lane * 16, sm + sl * SLOT + off);
    }
  }

  // loop-invariant fragment offsets (A within slot; X relative to its buffer)
  int aoff[2][2], xoff[2], woff[2];
#pragma unroll
  for (int mt = 0; mt < 2; ++mt)
#pragma unroll
    for (int kt = 0; kt < 2; ++kt)
      aoff[mt][kt] = ((wm << 5) + (mt << 4) + lm) * APITCH + (((kt << 5) + (quad << 3)) << 1);
#pragma unroll
  for (int kt = 0; kt < 2; ++kt)
    xoff[kt] = ((wn << 4) + lm) * APITCH + (((kt << 5) + (quad << 3)) << 1);
#pragma unroll
  for (int mt = 0; mt < 2; ++mt)
    woff[mt] = ((wn << 4) + lm) * APITCH + (((wm << 5) + (mt << 4) + (quad << 2)) << 1);

  // slot0 complete (5 outstanding = slot1), X writes flushed
  asm volatile("s_waitcnt vmcnt(5) lgkmcnt(0)" ::: "memory");
  __builtin_amdgcn_s_barrier();
  __builtin_amdgcn_sched_barrier(0);

  int bufA = 0;  // k % 3
  int xr = 0;    // k & 1
#pragma unroll 1
  for (int k = 0; k < 64; ++k) {
    const unsigned char* ab = sm + bufA * SLOT;
    // issue prefetch of slot k+2 into buffer (k+2)%3 (its last reader was
    // step k-1, which finished before the previous barrier)
    if (k < 62) {
      int nb = bufA + 2; if (nb >= 3) nb -= 3;
      const unsigned char* gsl = Aws + (t0 + k + 2) * SLOT;
      unsigned char* lb = sm + nb * SLOT;
#pragma unroll
      for (int r = 0; r < 5; ++r) {
        int off = ((r << 2) + wave) << 10;
        gload_lds16(gsl + off + lane * 16, lb + off);
      }
    }
    const unsigned char* xb = sm + LDS_X0 + xr * XBUF;
    half8 fa[2][2], fal[2][2], fxh[2], fxl[2];
#pragma unroll
    for (int mt = 0; mt < 2; ++mt)
#pragma unroll
      for (int kt = 0; kt < 2; ++kt) {
        fa[mt][kt]  = *reinterpret_cast<const half8*>(ab + aoff[mt][kt]);
        fal[mt][kt] = *reinterpret_cast<const half8*>(ab + AL_OFF + aoff[mt][kt]);
      }
#pragma unroll
    for (int kt = 0; kt < 2; ++kt) {
      fxh[kt] = *reinterpret_cast<const half8*>(xb + xoff[kt]);
      fxl[kt] = *reinterpret_cast<const half8*>(xb + XHALF + xoff[kt]);
    }
    float4 bv[2];
#pragma unroll
    for (int mt = 0; mt < 2; ++mt)
      bv[mt] = *reinterpret_cast<const float4*>(
          ab + BV_OFF + (((wm << 5) + (mt << 4) + (quad << 2)) << 2));
    float uu = *reinterpret_cast<const float*>(
        ab + U_OFF + ((b0 + (wn << 4) + lm) << 2));

    f32x4 acc[2] = {};
    __builtin_amdgcn_s_setprio(1);
#pragma unroll
    for (int mt = 0; mt < 2; ++mt)
#pragma unroll
      for (int kt = 0; kt < 2; ++kt) {
        acc[mt] = __builtin_amdgcn_mfma_f32_16x16x32_f16(fa[mt][kt],  fxh[kt], acc[mt], 0, 0, 0);
        acc[mt] = __builtin_amdgcn_mfma_f32_16x16x32_f16(fal[mt][kt], fxh[kt], acc[mt], 0, 0, 0);
        acc[mt] = __builtin_amdgcn_mfma_f32_16x16x32_f16(fa[mt][kt],  fxl[kt], acc[mt], 0, 0, 0);
      }
    __builtin_amdgcn_s_setprio(0);
    // += Bv[i] * u[b]
#pragma unroll
    for (int mt = 0; mt < 2; ++mt) {
      const float* bp = reinterpret_cast<const float*>(&bv[mt]);
#pragma unroll
      for (int e = 0; e < 4; ++e) acc[mt][e] += bp[e] * uu;
    }
    // write X_{k+1} into the OTHER X buffer (no WAR barrier needed) + out
    unsigned char* xw = sm + LDS_X0 + (xr ^ 1) * XBUF;
#pragma unroll
    for (int mt = 0; mt < 2; ++mt) {
      half4v hh, ll;
#pragma unroll
      for (int e = 0; e < 4; ++e) {
        float x = acc[mt][e];
        _Float16 h = (_Float16)x;
        hh[e] = h;
        ll[e] = (_Float16)(x - (float)h);
      }
      *reinterpret_cast<half4v*>(xw + woff[mt]) = hh;
      *reinterpret_cast<half4v*>(xw + XHALF + woff[mt]) = ll;
      const int bglob = b0 + (wn << 4) + lm;
      const int irow = (wm << 5) + (mt << 4) + (quad << 2);
      *reinterpret_cast<float4*>(&out[(((t0 + k) << 8) + bglob) * 64 + irow]) =
          make_float4(acc[mt][0], acc[mt][1], acc[mt][2], acc[mt][3]);
    }
    // single per-step sync with COUNTED vmcnt (never 0 in steady state).
    // Per-wave vmem queue at this point (oldest first):
    //  k=0:   [slot1(5)][slot2(5)][st0(2)]              -> after slot1 = 7
    //  1..61: [st k-2(2)][slot k+1(5)][st k-1(2)][slot k+2(5)][st k(2)] -> after = 9
    //  k=62:  [st60(2)][slot63(5)][st61(2)][st62(2)]    -> after = 4
    //  k=63:  no barrier (kernel end)
    if (k < 63) {
      if (k == 0)      asm volatile("s_waitcnt vmcnt(7) lgkmcnt(0)" ::: "memory");
      else if (k < 62) asm volatile("s_waitcnt vmcnt(9) lgkmcnt(0)" ::: "memory");
      else             asm volatile("s_waitcnt vmcnt(4) lgkmcnt(0)" ::: "memory");
      __builtin_amdgcn_s_barrier();
      __builtin_amdgcn_sched_barrier(0);
    }
    bufA = (bufA + 1 == 3) ? 0 : bufA + 1;
    xr ^= 1;
  }
}

extern "C" void kernel_launch(void* const* d_in, const int* in_sizes, int n_in,
                              void* d_out, int out_size, void* d_ws, size_t ws_size,
                              hipStream_t stream) {
  const float* inputs = (const float*)d_in[0];  // (4096, 256)
  const float* Ag     = (const float*)d_in[1];  // (4096, 64, 64)
  const float* Bg     = (const float*)d_in[2];  // (4096, 64)
  float* out = (float*)d_out;                   // (4096, 256, 64)

  const bool use_mfma = ws_size >= AWS_BYTES + OLD_WS_FLOATS * 4;
  unsigned char* Aws = (unsigned char*)d_ws;
  float* ws = (float*)((char*)d_ws + (use_mfma ? AWS_BYTES : 0));
  float* W  = ws + WS_W;
  float* Qw = ws + WS_Q;
  float* Pw = ws + WS_P;
  float* Zw = ws + WS_Z;
  float* Hw = ws + WS_H;

  if (use_mfma)
    k1_fused<<<256, 256, 0, stream>>>(Ag, Bg, inputs, Aws, W, Qw);
  else
    k1_suffix<<<256, 256, 0, stream>>>(Ag, Bg, W, Qw);
  k1b_combine<<<64, 256, 0, stream>>>(Qw, W, Pw);
  k1c_zgemm<<<256, 256, 0, stream>>>(inputs, W, Zw);
  k2_carry<<<64, 256, 0, stream>>>(Pw, Zw, Hw);
  if (use_mfma)
    k3_mfma<<<512, 256, 0, stream>>>(Aws, Hw, out);
  else
    k3_final<<<256, 256, 0, stream>>>(Ag, Bg, inputs, Hw, out);
}

// Round 5
// 575.409 us; speedup vs baseline: 1.0169x; 1.0169x over previous
//
#include <hip/hip_runtime.h>
#include <cstdint>

// HiPPO-LegS scan x_t = A_t x_{t-1} + B_t * u_t  via chunked parallel scan.
// L=4096, B=256, N=64.  Subchunks of 8 (512 blocks), superchunks of 64 (64).
// K1 (fused): suffix products + w_t per subchunk AND fp16 hi/lo slot production
//             512 blocks -> 2/CU; 8 serial steps (halved from 16)
// k1bc: combine 8 subchunks -> superchunk product P_s + upgrade w in LDS +
//       z-GEMM (K1c folded in; w rows never round-trip through global) (64 blocks)
// K2: sequential carry, double-buffered Pt/xb -> ONE barrier per step (64 blocks)
// K3 (MFMA): scan inside each superchunk; triple-buffered A-slot prefetch with
//            counted s_waitcnt vmcnt(N) + double-buffered X -> ONE barrier/step.
//            batch tile 32, grid 512, 2 blocks/CU.

#define TID ((int)threadIdx.x)

typedef _Float16 half8 __attribute__((ext_vector_type(8)));
typedef _Float16 half4v __attribute__((ext_vector_type(4)));
typedef float f32x4 __attribute__((ext_vector_type(4)));

constexpr int SUBL  = 8;    // subchunk length
constexpr int NSUB  = 512;  // 4096 / SUBL
constexpr int PAD   = 68;   // fp32 LDS row pad

// ws layout (floats)
constexpr size_t WS_W = 0;                       // 4096*64
constexpr size_t WS_Q = 262144;                  // NSUB*4096 = 2097152
constexpr size_t WS_P = WS_Q + 2097152;          // 64*4096
constexpr size_t WS_Z = WS_P + 262144;           // 64*256*64
constexpr size_t WS_H = WS_Z + 1048576;          // 64*256*64
constexpr size_t WS_TOT_FLOATS = WS_H + 1048576;

// A-slot layout for MFMA path (bytes per step t)
constexpr int SLOT   = 20480;   // 20 KB: 5 x (256 lanes x 16 B) staging chunks
constexpr int APITCH = 144;     // 72 fp16 per row (4-bank shift -> <=2-way conflicts)
constexpr int AL_OFF = 9216;    // Al array
constexpr int BV_OFF = 18432;   // Bv f32[64]
constexpr int U_OFF  = 18688;   // inputs row f32[256]
constexpr size_t AWS_BYTES = (size_t)4096 * SLOT;

// ---------------- shared helpers (fp32 path) ----------------
__device__ __forceinline__ void stage64x64(const float* __restrict__ g, float* __restrict__ l) {
#pragma unroll
  for (int r = 0; r < 4; ++r) {
    int id = TID + 256 * r;
    int i = id >> 4, j0 = (id & 15) << 2;
    *reinterpret_cast<float4*>(&l[i * PAD + j0]) =
        *reinterpret_cast<const float4*>(&g[i * 64 + j0]);
  }
}

__device__ __forceinline__ void matmul_tile(const float* __restrict__ Ml,
                                            const float* __restrict__ Al,
                                            float* __restrict__ Dl,
                                            int i_lo, int i_hi) {
  float acc[4][4];
#pragma unroll
  for (int a = 0; a < 4; ++a)
#pragma unroll
    for (int b = 0; b < 4; ++b) acc[a][b] = 0.f;
  const int j0 = i_hi << 2;
#pragma unroll
  for (int kq = 0; kq < 16; ++kq) {
    const int k0 = kq << 2;
    float4 mf[4], af[4];
#pragma unroll
    for (int a = 0; a < 4; ++a)
      mf[a] = *reinterpret_cast<const float4*>(&Ml[(i_lo + 16 * a) * PAD + k0]);
#pragma unroll
    for (int kk = 0; kk < 4; ++kk)
      af[kk] = *reinterpret_cast<const float4*>(&Al[(k0 + kk) * PAD + j0]);
#pragma unroll
    for (int a = 0; a < 4; ++a) {
      acc[a][0] += mf[a].x * af[0].x + mf[a].y * af[1].x + mf[a].z * af[2].x + mf[a].w * af[3].x;
      acc[a][1] += mf[a].x * af[0].y + mf[a].y * af[1].y + mf[a].z * af[2].y + mf[a].w * af[3].y;
      acc[a][2] += mf[a].x * af[0].z + mf[a].y * af[1].z + mf[a].z * af[2].z + mf[a].w * af[3].z;
      acc[a][3] += mf[a].x * af[0].w + mf[a].y * af[1].w + mf[a].z * af[2].w + mf[a].w * af[3].w;
    }
  }
#pragma unroll
  for (int a = 0; a < 4; ++a)
    *reinterpret_cast<float4*>(&Dl[(i_lo + 16 * a) * PAD + j0]) =
        make_float4(acc[a][0], acc[a][1], acc[a][2], acc[a][3]);
}

// ---------------- K1 fused: suffix products + w_t + fp16 hi/lo slots ----------------
__global__ __launch_bounds__(256) void k1_fused(const float* __restrict__ Ag,
                                                const float* __restrict__ Bg,
                                                const float* __restrict__ inp,
                                                unsigned char* __restrict__ Aws,
                                                float* __restrict__ W,
                                                float* __restrict__ Qw) {
  __shared__ float Ms[2][64 * PAD];
  __shared__ float As[2][64 * PAD];
  __shared__ float Bvs[2][64];
  const int c = blockIdx.x;
  const int i_lo = TID & 15, i_hi = TID >> 4;
  const int r_i0 = TID >> 4;          // staged rows: r_i0 + 16*r
  const int r_j0 = (TID & 15) << 2;   // staged cols: r_j0 .. r_j0+3

  for (int idx = TID; idx < 64 * PAD; idx += 256) Ms[0][idx] = 0.f;

  // prologue: A(last), Bv(last) -> regs
  float4 pc[4];
  float4 bvc = make_float4(0.f, 0.f, 0.f, 0.f);
  {
    const float* g = Ag + (size_t)(c * SUBL + SUBL - 1) * 4096;
#pragma unroll
    for (int r = 0; r < 4; ++r)
      pc[r] = *reinterpret_cast<const float4*>(&g[(r_i0 + 16 * r) * 64 + r_j0]);
    if (TID < 16)
      bvc = *reinterpret_cast<const float4*>(&Bg[(size_t)(c * SUBL + SUBL - 1) * 64 + TID * 4]);
  }
  __syncthreads();
  if (TID < 64) Ms[0][TID * PAD + TID] = 1.f;
#pragma unroll
  for (int r = 0; r < 4; ++r)
    *reinterpret_cast<float4*>(&As[0][(r_i0 + 16 * r) * PAD + r_j0]) = pc[r];
  if (TID < 16) *reinterpret_cast<float4*>(&Bvs[0][TID * 4]) = bvc;
  __syncthreads();

  int cur = 0, ab = 0;
  for (int k = SUBL - 1; k >= 0; --k) {
    const int t = c * SUBL + k;
    unsigned char* slot = Aws + (size_t)t * SLOT;
    // prefetch next step's A, Bv into regs (latency hidden under this step)
    float4 pn[4];
    float4 bvn = make_float4(0.f, 0.f, 0.f, 0.f);
    if (k > 0) {
      const float* g = Ag + (size_t)(t - 1) * 4096;
#pragma unroll
      for (int r = 0; r < 4; ++r)
        pn[r] = *reinterpret_cast<const float4*>(&g[(r_i0 + 16 * r) * 64 + r_j0]);
      if (TID < 16)
        bvn = *reinterpret_cast<const float4*>(&Bg[(size_t)(t - 1) * 64 + TID * 4]);
    }
    // u-row copy to slot
    if (TID >= 64 && TID < 128) {
      int q = TID - 64;
      *reinterpret_cast<float4*>(slot + U_OFF + q * 16) =
          *reinterpret_cast<const float4*>(inp + (size_t)t * 256 + q * 4);
    }
    // Bv slot write (regs held from previous iteration)
    if (TID < 16) *reinterpret_cast<float4*>(slot + BV_OFF + TID * 16) = bvc;
    // w_t = M_suffix @ Bv
    if (TID < 64) {
      float wv = 0.f;
#pragma unroll
      for (int kq = 0; kq < 16; ++kq) {
        float4 m = *reinterpret_cast<const float4*>(&Ms[cur][TID * PAD + kq * 4]);
        float4 b = *reinterpret_cast<const float4*>(&Bvs[ab][kq * 4]);
        wv += m.x * b.x + m.y * b.y + m.z * b.z + m.w * b.w;
      }
      W[t * 64 + TID] = wv;
    }
    // fp16 hi/lo split from registers -> global slot
#pragma unroll
    for (int r = 0; r < 4; ++r) {
      float vv[4] = {pc[r].x, pc[r].y, pc[r].z, pc[r].w};
      half4v hh, ll;
#pragma unroll
      for (int e = 0; e < 4; ++e) {
        _Float16 h = (_Float16)vv[e];
        hh[e] = h;
        ll[e] = (_Float16)(vv[e] - (float)h);
      }
      const int row = r_i0 + 16 * r;
      *reinterpret_cast<half4v*>(slot + row * APITCH + r_j0 * 2) = hh;
      *reinterpret_cast<half4v*>(slot + AL_OFF + row * APITCH + r_j0 * 2) = ll;
    }
    if (TID < 64) {  // zero row pad (cols 64..71)
      half8 z = {};
      *reinterpret_cast<half8*>(slot + TID * APITCH + 128) = z;
      *reinterpret_cast<half8*>(slot + AL_OFF + TID * APITCH + 128) = z;
    }
    // suffix product
    matmul_tile(Ms[cur], As[ab], Ms[cur ^ 1], i_lo, i_hi);
    // late write of prefetched data into the other LDS buffers
    if (k > 0) {
#pragma unroll
      for (int r = 0; r < 4; ++r)
        *reinterpret_cast<float4*>(&As[ab ^ 1][(r_i0 + 16 * r) * PAD + r_j0]) = pn[r];
      if (TID < 16) *reinterpret_cast<float4*>(&Bvs[ab ^ 1][TID * 4]) = bvn;
#pragma unroll
      for (int r = 0; r < 4; ++r) pc[r] = pn[r];
      bvc = bvn;
    }
    __syncthreads();
    cur ^= 1;
    ab ^= 1;
  }
#pragma unroll
  for (int r = 0; r < 4; ++r) {
    int id = TID + 256 * r;
    int i = id >> 4, j0 = (id & 15) << 2;
    *reinterpret_cast<float4*>(&Qw[(size_t)c * 4096 + i * 64 + j0]) =
        *reinterpret_cast<const float4*>(&Ms[cur][i * PAD + j0]);
  }
}

// ---------------- K1 (fp32 fallback, no slot production) ----------------
__global__ __launch_bounds__(256) void k1_suffix(const float* __restrict__ Ag,
                                                 const float* __restrict__ Bg,
                                                 float* __restrict__ W,
                                                 float* __restrict__ Qw) {
  __shared__ float Ms[2][64 * PAD];
  __shared__ float As[64 * PAD];
  __shared__ float Bvs[64];
  const int c = blockIdx.x;
  const int i_lo = TID & 15, i_hi = TID >> 4;
  for (int idx = TID; idx < 64 * PAD; idx += 256) Ms[0][idx] = 0.f;
  __syncthreads();
  if (TID < 64) Ms[0][TID * PAD + TID] = 1.f;
  int cur = 0;
  for (int k = SUBL - 1; k >= 0; --k) {
    const int t = c * SUBL + k;
    stage64x64(Ag + (size_t)t * 4096, As);
    if (TID < 16)
      *reinterpret_cast<float4*>(&Bvs[TID * 4]) =
          *reinterpret_cast<const float4*>(&Bg[t * 64 + TID * 4]);
    __syncthreads();
    if (TID < 64) {
      float wv = 0.f;
#pragma unroll
      for (int kq = 0; kq < 16; ++kq) {
        float4 m = *reinterpret_cast<const float4*>(&Ms[cur][TID * PAD + kq * 4]);
        float4 b = *reinterpret_cast<const float4*>(&Bvs[kq * 4]);
        wv += m.x * b.x + m.y * b.y + m.z * b.z + m.w * b.w;
      }
      W[t * 64 + TID] = wv;
    }
    matmul_tile(Ms[cur], As, Ms[cur ^ 1], i_lo, i_hi);
    __syncthreads();
    cur ^= 1;
  }
#pragma unroll
  for (int r = 0; r < 4; ++r) {
    int id = TID + 256 * r;
    int i = id >> 4, j0 = (id & 15) << 2;
    *reinterpret_cast<float4*>(&Qw[(size_t)c * 4096 + i * 64 + j0]) =
        *reinterpret_cast<const float4*>(&Ms[cur][i * PAD + j0]);
  }
}

// ---------------- k1bc: combine 8 subchunks + upgrade w (LDS) + z-GEMM ----------------
__global__ __launch_bounds__(256) void k1bc(const float* __restrict__ Qw,
                                            const float* __restrict__ W,
                                            const float* __restrict__ inp,
                                            float* __restrict__ Pw,
                                            float* __restrict__ Zw) {
  __shared__ float R[2][64 * PAD];
  __shared__ float Qs[64 * PAD];     // reused as inT in z-phase
  __shared__ float Wall[64 * PAD];   // upgraded w rows [t-local 0..63][i]
  const int s = blockIdx.x;
  const int i_lo = TID & 15, i_hi = TID >> 4;
  int cur = 0;
  // ---- combine phase: P_s = Q7 Q6 ... Q0, upgrade w rows in Wall ----
  for (int m = 7; m >= 0; --m) {
    const int c = 8 * s + m;
    stage64x64(Qw + (size_t)c * 4096, Qs);
    if (TID < 128) {  // load this subchunk's 8 w rows
      int tt = TID >> 4, i0 = (TID & 15) << 2;
      *reinterpret_cast<float4*>(&Wall[(m * 8 + tt) * PAD + i0]) =
          *reinterpret_cast<const float4*>(&W[(size_t)(c * 8 + tt) * 64 + i0]);
    }
    __syncthreads();
    if (m < 7) {
      // upgrade: w_new[i] = sum_k R[i,k] * w_old[k]  (R = Q_{m+1..7})
      const int th = TID >> 5, ib = TID & 31;  // th = t-row 0..7, outputs i=ib, ib+32
      float a0 = 0.f, a1 = 0.f;
#pragma unroll
      for (int kq = 0; kq < 16; ++kq) {
        const int k0 = kq << 2;
        float4 wf = *reinterpret_cast<const float4*>(&Wall[(m * 8 + th) * PAD + k0]);
        float4 r0 = *reinterpret_cast<const float4*>(&R[cur][ib * PAD + k0]);
        float4 r1 = *reinterpret_cast<const float4*>(&R[cur][(ib + 32) * PAD + k0]);
        a0 += r0.x * wf.x + r0.y * wf.y + r0.z * wf.z + r0.w * wf.w;
        a1 += r1.x * wf.x + r1.y * wf.y + r1.z * wf.z + r1.w * wf.w;
      }
      matmul_tile(R[cur], Qs, R[cur ^ 1], i_lo, i_hi);
      __syncthreads();
      Wall[(m * 8 + th) * PAD + ib] = a0;
      Wall[(m * 8 + th) * PAD + ib + 32] = a1;
    } else {
#pragma unroll
      for (int r = 0; r < 4; ++r) {
        int id = TID + 256 * r;
        int i = id >> 4, j0 = (id & 15) << 2;
        *reinterpret_cast<float4*>(&R[cur ^ 1][i * PAD + j0]) =
            *reinterpret_cast<const float4*>(&Qs[i * PAD + j0]);
      }
    }
    __syncthreads();
    cur ^= 1;
  }
  // write P_s
#pragma unroll
  for (int r = 0; r < 4; ++r) {
    int id = TID + 256 * r;
    int i = id >> 4, j0 = (id & 15) << 2;
    *reinterpret_cast<float4*>(&Pw[(size_t)s * 4096 + i * 64 + j0]) =
        *reinterpret_cast<const float4*>(&R[cur][i * PAD + j0]);
  }
  __syncthreads();
  // ---- z-phase: z_s[b,i] = sum_t inp[t,b] * Wall[t][i], 4 batch groups ----
  const int t0 = s * 64;
  const int j0c = i_hi << 2;
  for (int g = 0; g < 4; ++g) {
    const int b0 = 64 * g;
    // stage inputs transposed into Qs: Qs[b-local][t-local]
#pragma unroll
    for (int r = 0; r < 4; ++r) {
      int id = TID + 256 * r;
      int tl = id >> 4, b4 = (id & 15) << 2;
      float4 v = *reinterpret_cast<const float4*>(&inp[(size_t)(t0 + tl) * 256 + b0 + b4]);
      Qs[(b4 + 0) * PAD + tl] = v.x;
      Qs[(b4 + 1) * PAD + tl] = v.y;
      Qs[(b4 + 2) * PAD + tl] = v.z;
      Qs[(b4 + 3) * PAD + tl] = v.w;
    }
    __syncthreads();
    float acc[4][4];
#pragma unroll
    for (int a = 0; a < 4; ++a)
#pragma unroll
      for (int q = 0; q < 4; ++q) acc[a][q] = 0.f;
#pragma unroll
    for (int kq = 0; kq < 16; ++kq) {
      const int k0 = kq << 2;
      float4 bf[4], wf[4];
#pragma unroll
      for (int a = 0; a < 4; ++a)
        bf[a] = *reinterpret_cast<const float4*>(&Qs[(i_lo + 16 * a) * PAD + k0]);
#pragma unroll
      for (int kk = 0; kk < 4; ++kk)
        wf[kk] = *reinterpret_cast<const float4*>(&Wall[(k0 + kk) * PAD + j0c]);
#pragma unroll
      for (int a = 0; a < 4; ++a) {
        acc[a][0] += bf[a].x * wf[0].x + bf[a].y * wf[1].x + bf[a].z * wf[2].x + bf[a].w * wf[3].x;
        acc[a][1] += bf[a].x * wf[0].y + bf[a].y * wf[1].y + bf[a].z * wf[2].y + bf[a].w * wf[3].y;
        acc[a][2] += bf[a].x * wf[0].z + bf[a].y * wf[1].z + bf[a].z * wf[2].z + bf[a].w * wf[3].z;
        acc[a][3] += bf[a].x * wf[0].w + bf[a].y * wf[1].w + bf[a].z * wf[2].w + bf[a].w * wf[3].w;
      }
    }
    __syncthreads();
    // stage to R[0] for coalesced Zw write
#pragma unroll
    for (int a = 0; a < 4; ++a)
      *reinterpret_cast<float4*>(&R[0][(i_lo + 16 * a) * PAD + j0c]) =
          make_float4(acc[a][0], acc[a][1], acc[a][2], acc[a][3]);
    __syncthreads();
#pragma unroll
    for (int r = 0; r < 4; ++r) {
      int id = TID + 256 * r;
      int bl = id >> 4, i0 = (id & 15) << 2;
      *reinterpret_cast<float4*>(&Zw[(size_t)s * 16384 + (b0 + bl) * 64 + i0]) =
          *reinterpret_cast<const float4*>(&R[0][bl * PAD + i0]);
    }
  }
}

// ---------------- K2: sequential carry, double-buffered -> one barrier/step ----------------
__global__ __launch_bounds__(256) void k2_carry(const float* __restrict__ Pw,
                                                const float* __restrict__ Zw,
                                                float* __restrict__ Hw) {
  __shared__ float Pt[2][64 * PAD];
  __shared__ float xb[2][4 * PAD];
  const int g = blockIdx.x;
  const int bl = TID >> 6, i = TID & 63;
  const int bg = 4 * g + bl;
  const int ir = TID >> 4, j0 = (TID & 15) << 2;
  for (int idx = TID; idx < 4 * PAD; idx += 256) xb[0][idx] = 0.f;
  // prologue: stage P(0) transposed + z(0)
  float4 p0[4];
#pragma unroll
  for (int r = 0; r < 4; ++r)
    p0[r] = *reinterpret_cast<const float4*>(&Pw[(ir + 16 * r) * 64 + j0]);
  float zc = Zw[(size_t)bg * 64 + i];
#pragma unroll
  for (int r = 0; r < 4; ++r) {
    int row = ir + 16 * r;
    Pt[0][(j0 + 0) * PAD + row] = p0[r].x;
    Pt[0][(j0 + 1) * PAD + row] = p0[r].y;
    Pt[0][(j0 + 2) * PAD + row] = p0[r].z;
    Pt[0][(j0 + 3) * PAD + row] = p0[r].w;
  }
  __syncthreads();
  float h = 0.f;
  for (int s = 0; s < 64; ++s) {
    const int rb = s & 1, wb = rb ^ 1;
    float4 pn[4];
    float zn = 0.f;
    if (s < 63) {
#pragma unroll
      for (int r = 0; r < 4; ++r)
        pn[r] = *reinterpret_cast<const float4*>(
            &Pw[(size_t)(s + 1) * 4096 + (ir + 16 * r) * 64 + j0]);
      zn = Zw[(size_t)(s + 1) * 16384 + bg * 64 + i];
    }
    Hw[(size_t)s * 16384 + bg * 64 + i] = h;
    float acc = zc;
#pragma unroll
    for (int jq = 0; jq < 16; ++jq) {
      const int jj = jq << 2;
      float4 xf = *reinterpret_cast<const float4*>(&xb[rb][bl * PAD + jj]);
      acc += Pt[rb][(jj + 0) * PAD + i] * xf.x + Pt[rb][(jj + 1) * PAD + i] * xf.y +
             Pt[rb][(jj + 2) * PAD + i] * xf.z + Pt[rb][(jj + 3) * PAD + i] * xf.w;
    }
    h = acc;
    xb[wb][bl * PAD + i] = h;
    if (s < 63) {
#pragma unroll
      for (int r = 0; r < 4; ++r) {
        int row = ir + 16 * r;
        Pt[wb][(j0 + 0) * PAD + row] = pn[r].x;
        Pt[wb][(j0 + 1) * PAD + row] = pn[r].y;
        Pt[wb][(j0 + 2) * PAD + row] = pn[r].z;
        Pt[wb][(j0 + 3) * PAD + row] = pn[r].w;
      }
      zc = zn;
    }
    __syncthreads();
  }
}

// ---------------- K3 (fp32 fallback) ----------------
__global__ __launch_bounds__(256) void k3_final(const float* __restrict__ Ag,
                                                const float* __restrict__ Bg,
                                                const float* __restrict__ inp,
                                                const float* __restrict__ Hw,
                                                float* __restrict__ out) {
  __shared__ float As[64 * PAD];
  __shared__ float xs[64 * PAD];
  __shared__ float Bvs[64];
  __shared__ float ins[64];
  const int s = blockIdx.x >> 2, g = blockIdx.x & 3;
  const int b0 = 64 * g;
  const int i_lo = TID & 15, i_hi = TID >> 4;
#pragma unroll
  for (int r = 0; r < 4; ++r) {
    int id = TID + 256 * r;
    int bl = id >> 4, i0 = (id & 15) << 2;
    *reinterpret_cast<float4*>(&xs[bl * PAD + i0]) =
        *reinterpret_cast<const float4*>(&Hw[(size_t)s * 16384 + (b0 + bl) * 64 + i0]);
  }
  for (int k = 0; k < 64; ++k) {
    const int t = s * 64 + k;
    stage64x64(Ag + (size_t)t * 4096, As);
    if (TID < 16)
      *reinterpret_cast<float4*>(&Bvs[TID * 4]) =
          *reinterpret_cast<const float4*>(&Bg[t * 64 + TID * 4]);
    if (TID >= 64 && TID < 80) {
      int q = TID - 64;
      *reinterpret_cast<float4*>(&ins[q * 4]) =
          *reinterpret_cast<const float4*>(&inp[(size_t)t * 256 + b0 + q * 4]);
    }
    __syncthreads();
    float acc[4][4];
#pragma unroll
    for (int a = 0; a < 4; ++a)
#pragma unroll
      for (int r = 0; r < 4; ++r) acc[a][r] = 0.f;
#pragma unroll
    for (int jq = 0; jq < 16; ++jq) {
      const int j0 = jq << 2;
      float4 af[4], xf[4];
#pragma unroll
      for (int a = 0; a < 4; ++a)
        af[a] = *reinterpret_cast<const float4*>(&As[(i_lo + 16 * a) * PAD + j0]);
#pragma unroll
      for (int r = 0; r < 4; ++r)
        xf[r] = *reinterpret_cast<const float4*>(&xs[(i_hi + 16 * r) * PAD + j0]);
#pragma unroll
      for (int a = 0; a < 4; ++a)
#pragma unroll
        for (int r = 0; r < 4; ++r)
          acc[a][r] += af[a].x * xf[r].x + af[a].y * xf[r].y + af[a].z * xf[r].z + af[a].w * xf[r].w;
    }
    float bv[4], ui[4];
#pragma unroll
    for (int a = 0; a < 4; ++a) bv[a] = Bvs[i_lo + 16 * a];
#pragma unroll
    for (int r = 0; r < 4; ++r) ui[r] = ins[i_hi + 16 * r];
#pragma unroll
    for (int a = 0; a < 4; ++a)
#pragma unroll
      for (int r = 0; r < 4; ++r) acc[a][r] += bv[a] * ui[r];
    __syncthreads();
#pragma unroll
    for (int r = 0; r < 4; ++r)
#pragma unroll
      for (int a = 0; a < 4; ++a)
        xs[(i_hi + 16 * r) * PAD + i_lo + 16 * a] = acc[a][r];
    __syncthreads();
#pragma unroll
    for (int r = 0; r < 4; ++r) {
      int id = TID + 256 * r;
      int bl = id >> 4, i0 = (id & 15) << 2;
      *reinterpret_cast<float4*>(&out[((size_t)t * 256 + b0 + bl) * 64 + i0]) =
          *reinterpret_cast<const float4*>(&xs[bl * PAD + i0]);
    }
  }
}

// ---------------- K3 (MFMA fp16 hi/lo, counted-vmcnt pipeline) ----------------
__device__ __forceinline__ void gload_lds16(const void* g, void* l) {
  __builtin_amdgcn_global_load_lds(
      (const __attribute__((address_space(1))) unsigned int*)g,
      (__attribute__((address_space(3))) unsigned int*)l, 16, 0, 0);
}

constexpr int XROWS  = 32;
constexpr int XHALF  = XROWS * APITCH;       // 4608 (one of hi/lo)
constexpr int XBUF   = 2 * XHALF;            // 9216 (hi+lo)
constexpr int LDS_X0 = 3 * SLOT;             // 61440 (3 A-slot buffers)
constexpr int LDS_SZ = LDS_X0 + 2 * XBUF;    // 79872 -> 2 blocks/CU

__global__ __launch_bounds__(256, 2) void k3_mfma(const unsigned char* __restrict__ Aws,
                                                  const float* __restrict__ Hw,
                                                  float* __restrict__ out) {
  __shared__ __align__(16) unsigned char sm[LDS_SZ];
  const int blk = blockIdx.x;
  const int s = (blk & 7) | ((blk >> 6) << 3);
  const int g = (blk >> 3) & 7;
  const int b0 = g << 5;
  const int lane = TID & 63, wave = TID >> 6;
  const int lm = lane & 15, quad = lane >> 4;
  const int wm = wave >> 1, wn = wave & 1;

#pragma unroll
  for (int r = 0; r < 2; ++r) {
    int id = TID + (r << 8);
    int bl = id >> 4, j0 = (id & 15) << 2;
    float4 v = *reinterpret_cast<const float4*>(
        &Hw[(size_t)s * 16384 + (size_t)(b0 + bl) * 64 + j0]);
    float vv[4] = {v.x, v.y, v.z, v.w};
    half4v hh, ll;
#pragma unroll
    for (int e = 0; e < 4; ++e) {
      _Float16 h = (_Float16)vv[e];
      hh[e] = h;
      ll[e] = (_Float16)(vv[e] - (float)h);
    }
    *reinterpret_cast<half4v*>(sm + LDS_X0 + bl * APITCH + (j0 << 1)) = hh;
    *reinterpret_cast<half4v*>(sm + LDS_X0 + XHALF + bl * APITCH + (j0 << 1)) = ll;
  }

  const size_t t0 = (size_t)s * 64;
#pragma unroll
  for (int sl = 0; sl < 2; ++sl) {
    const unsigned char* gsl = Aws + (t0 + sl) * SLOT;
#pragma unroll
    for (int r = 0; r < 5; ++r) {
      int off = ((r << 2) + wave) << 10;
      gload_lds16(gsl + off + lane * 16, sm + sl * SLOT + off);
    }
  }

  int aoff[2][2], xoff[2], woff[2];
#pragma unroll
  for (int mt = 0; mt < 2; ++mt)
#pragma unroll
    for (int kt = 0; kt < 2; ++kt)
      aoff[mt][kt] = ((wm << 5) + (mt << 4) + lm) * APITCH + (((kt << 5) + (quad << 3)) << 1);
#pragma unroll
  for (int kt = 0; kt < 2; ++kt)
    xoff[kt] = ((wn << 4) + lm) * APITCH + (((kt << 5) + (quad << 3)) << 1);
#pragma unroll
  for (int mt = 0; mt < 2; ++mt)
    woff[mt] = ((wn << 4) + lm) * APITCH + (((wm << 5) + (mt << 4) + (quad << 2)) << 1);

  asm volatile("s_waitcnt vmcnt(5) lgkmcnt(0)" ::: "memory");
  __builtin_amdgcn_s_barrier();
  __builtin_amdgcn_sched_barrier(0);

  int bufA = 0;
  int xr = 0;
#pragma unroll 1
  for (int k = 0; k < 64; ++k) {
    const unsigned char* ab = sm + bufA * SLOT;
    if (k < 62) {
      int nb = bufA + 2; if (nb >= 3) nb -= 3;
      const unsigned char* gsl = Aws + (t0 + k + 2) * SLOT;
      unsigned char* lb = sm + nb * SLOT;
#pragma unroll
      for (int r = 0; r < 5; ++r) {
        int off = ((r << 2) + wave) << 10;
        gload_lds16(gsl + off + lane * 16, lb + off);
      }
    }
    const unsigned char* xb = sm + LDS_X0 + xr * XBUF;
    half8 fa[2][2], fal[2][2], fxh[2], fxl[2];
#pragma unroll
    for (int mt = 0; mt < 2; ++mt)
#pragma unroll
      for (int kt = 0; kt < 2; ++kt) {
        fa[mt][kt]  = *reinterpret_cast<const half8*>(ab + aoff[mt][kt]);
        fal[mt][kt] = *reinterpret_cast<const half8*>(ab + AL_OFF + aoff[mt][kt]);
      }
#pragma unroll
    for (int kt = 0; kt < 2; ++kt) {
      fxh[kt] = *reinterpret_cast<const half8*>(xb + xoff[kt]);
      fxl[kt] = *reinterpret_cast<const half8*>(xb + XHALF + xoff[kt]);
    }
    float4 bv[2];
#pragma unroll
    for (int mt = 0; mt < 2; ++mt)
      bv[mt] = *reinterpret_cast<const float4*>(
          ab + BV_OFF + (((wm << 5) + (mt << 4) + (quad << 2)) << 2));
    float uu = *reinterpret_cast<const float*>(
        ab + U_OFF + ((b0 + (wn << 4) + lm) << 2));

    f32x4 acc[2] = {};
    __builtin_amdgcn_s_setprio(1);
#pragma unroll
    for (int mt = 0; mt < 2; ++mt)
#pragma unroll
      for (int kt = 0; kt < 2; ++kt) {
        acc[mt] = __builtin_amdgcn_mfma_f32_16x16x32_f16(fa[mt][kt],  fxh[kt], acc[mt], 0, 0, 0);
        acc[mt] = __builtin_amdgcn_mfma_f32_16x16x32_f16(fal[mt][kt], fxh[kt], acc[mt], 0, 0, 0);
        acc[mt] = __builtin_amdgcn_mfma_f32_16x16x32_f16(fa[mt][kt],  fxl[kt], acc[mt], 0, 0, 0);
      }
    __builtin_amdgcn_s_setprio(0);
#pragma unroll
    for (int mt = 0; mt < 2; ++mt) {
      const float* bp = reinterpret_cast<const float*>(&bv[mt]);
#pragma unroll
      for (int e = 0; e < 4; ++e) acc[mt][e] += bp[e] * uu;
    }
    unsigned char* xw = sm + LDS_X0 + (xr ^ 1) * XBUF;
#pragma unroll
    for (int mt = 0; mt < 2; ++mt) {
      half4v hh, ll;
#pragma unroll
      for (int e = 0; e < 4; ++e) {
        float x = acc[mt][e];
        _Float16 h = (_Float16)x;
        hh[e] = h;
        ll[e] = (_Float16)(x - (float)h);
      }
      *reinterpret_cast<half4v*>(xw + woff[mt]) = hh;
      *reinterpret_cast<half4v*>(xw + XHALF + woff[mt]) = ll;
      const int bglob = b0 + (wn << 4) + lm;
      const int irow = (wm << 5) + (mt << 4) + (quad << 2);
      *reinterpret_cast<float4*>(&out[(((t0 + k) << 8) + bglob) * 64 + irow]) =
          make_float4(acc[mt][0], acc[mt][1], acc[mt][2], acc[mt][3]);
    }
    if (k < 63) {
      if (k == 0)      asm volatile("s_waitcnt vmcnt(7) lgkmcnt(0)" ::: "memory");
      else if (k < 62) asm volatile("s_waitcnt vmcnt(9) lgkmcnt(0)" ::: "memory");
      else             asm volatile("s_waitcnt vmcnt(4) lgkmcnt(0)" ::: "memory");
      __builtin_amdgcn_s_barrier();
      __builtin_amdgcn_sched_barrier(0);
    }
    bufA = (bufA + 1 == 3) ? 0 : bufA + 1;
    xr ^= 1;
  }
}

extern "C" void kernel_launch(void* const* d_in, const int* in_sizes, int n_in,
                              void* d_out, int out_size, void* d_ws, size_t ws_size,
                              hipStream_t stream) {
  const float* inputs = (const float*)d_in[0];  // (4096, 256)
  const float* Ag     = (const float*)d_in[1];  // (4096, 64, 64)
  const float* Bg     = (const float*)d_in[2];  // (4096, 64)
  float* out = (float*)d_out;                   // (4096, 256, 64)

  const bool use_mfma = ws_size >= AWS_BYTES + WS_TOT_FLOATS * 4;
  unsigned char* Aws = (unsigned char*)d_ws;
  float* ws = (float*)((char*)d_ws + (use_mfma ? AWS_BYTES : 0));
  float* W  = ws + WS_W;
  float* Qw = ws + WS_Q;
  float* Pw = ws + WS_P;
  float* Zw = ws + WS_Z;
  float* Hw = ws + WS_H;

  if (use_mfma)
    k1_fused<<<NSUB, 256, 0, stream>>>(Ag, Bg, inputs, Aws, W, Qw);
  else
    k1_suffix<<<NSUB, 256, 0, stream>>>(Ag, Bg, W, Qw);
  k1bc<<<64, 256, 0, stream>>>(Qw, W, inputs, Pw, Zw);
  k2_carry<<<64, 256, 0, stream>>>(Pw, Zw, Hw);
  if (use_mfma)
    k3_mfma<<<512, 256, 0, stream>>>(Aws, Hw, out);
  else
    k3_final<<<256, 256, 0, stream>>>(Ag, Bg, inputs, Hw, out);
}